// Round 23
// baseline (42.011 us; speedup 1.0000x reference)
//
#include <hip/hip_runtime.h>
#include <stdint.h>

#define CLASS_NUM 7
#define QROWS 1050
#define QPAD  1152              // 72 groups * 16 rows; pad rows are zero
#define NPAD  102               // pad rows each add exp2(0)=1 to denom
#define NGRP  72
#define GPW   18                // groups per wave (one queue quarter)
#define QSUM_OFF (QPAD * 128)   // 147456: 7x128 fp32 class sums (after fp8 image)
#define PART_OFF 151552         // per-block partials
#define NBLK  1024
#define C2L 2.8853900817779268f // 2/ln2 : exp(2s) = exp2(s*C2L)
#define USCALE 0x7F7F7F7F       // unit E8M0 scales (127 -> 2^0)

typedef float f32x4 __attribute__((ext_vector_type(4)));
typedef int   i32x8 __attribute__((ext_vector_type(8)));

__device__ __forceinline__ float fexp2(float x) { return __builtin_amdgcn_exp2f(x); }

// pack 4 floats -> 4 fp8 e4m3 (OCP, RNE) in one dword
__device__ __forceinline__ unsigned pk8(float a, float b, float c, float d) {
  int v = __builtin_amdgcn_cvt_pk_fp8_f32(a, b, 0, false);
  v = __builtin_amdgcn_cvt_pk_fp8_f32(c, d, v, true);
  return (unsigned)v;
}

// ---- prep (single dispatch): blocks 0-71 -> fp8 K=128-fragment queue image
// (lane l of group g holds Q[g*16+(l&15)][(l>>4)*32 .. +32]); blocks 72-78 ->
// per-class column sums.  (unchanged, verified)
__global__ __launch_bounds__(256) void prep_q8(
    const float* __restrict__ queue, char* __restrict__ ws)
{
  const int b = blockIdx.x, tid = threadIdx.x;
  if (b < NGRP) {
    const int g = b;
    const int lane = tid >> 2, k = tid & 3;
    const int row = g * 16 + (lane & 15);
    const int col = (lane >> 4) * 32 + k * 8;
    uint2 u = {0u, 0u};
    if (row < QROWS) {
      const float4 v0 = *(const float4*)(queue + row * 128 + col);
      const float4 v1 = *(const float4*)(queue + row * 128 + col + 4);
      u.x = pk8(v0.x, v0.y, v0.z, v0.w);
      u.y = pk8(v1.x, v1.y, v1.z, v1.w);
    }
    *(uint2*)(ws + (size_t)g * 2048 + tid * 8) = u;
  } else if (tid < 128) {
    const int c = b - NGRP, d = tid;
    float s = 0.f;
    const float* p = queue + c * 150 * 128 + d;
#pragma unroll 10
    for (int i = 0; i < 150; ++i) s += p[i * 128];
    ((float*)(ws + QSUM_OFF))[c * 128 + d] = s;
  }
}

// ---- fused main: 1024 blocks x 256 thr (4 waves), 64 B-rows/block.
// act/ema staged via global_load_lds DMA (MLP decoupled from VGPRs), prologue
// recomputed from LDS; MX K=128 sweep unchanged from verified R22 kernel.
__global__ __launch_bounds__(256, 2) void pgc_stream(
    const float* __restrict__ act, const float* __restrict__ ema,
    const float* __restrict__ plab, char* __restrict__ ws)
{
  __shared__ __align__(16) char smem[75520];
  char*  stage  = smem;                        // 64 KB: act[32K] || ema[32K]
  char*  aT     = smem + 65536;                // 8 KB fp8 A tile, K=128 frags
  int*   s_lab  = (int*)  (smem + 73728);      // [64]
  float* s_lpos = (float*)(smem + 73984);      // [64]
  float* s_pd   = (float*)(smem + 74240);      // [64]
  float (*dnp)[64] = (float(*)[64])(smem + 74496);  // [4][64]

  const int tid = threadIdx.x, lane = tid & 63, wave = tid >> 6;
  const int lo = lane & 15, hi = lane >> 4;

  // ---- DMA: stage this block's 32KB act + 32KB ema into LDS (async, 16
  // instrs/wave, ~64KB in flight per block — no VGPR round-trip).
  {
    const char* actB = (const char*)(act + (size_t)blockIdx.x * 64 * 128);
    const char* emaB = (const char*)(ema + (size_t)blockIdx.x * 64 * 128);
    const char* src = (wave < 2) ? actB + wave * 16384 : emaB + (wave - 2) * 16384;
    char* dst = stage + wave * 16384;
#pragma unroll
    for (int i = 0; i < 16; ++i)
      __builtin_amdgcn_global_load_lds(
          (const __attribute__((address_space(1))) void*)(src + i * 1024 + lane * 16),
          (__attribute__((address_space(3))) void*)(dst + i * 1024), 16, 0, 0);
  }

  // labels while the DMA flies (independent global loads)
  if (tid < 64) {
    const float* pp = plab + ((size_t)blockIdx.x * 64 + tid) * CLASS_NUM;
    float best = pp[0]; int bi = 0;
#pragma unroll
    for (int c = 1; c < CLASS_NUM; ++c) {
      const float v = pp[c];
      if (v > best) { best = v; bi = c; }
    }
    s_lab[tid] = bi;
  }
  __syncthreads();   // DMA drained (barrier waits vmcnt) + labels visible

  // ---- prologue from LDS: thread owns 4 floats of row (tid>>5)+8k, k=0..7.
  // Conflict-free linear ds_read_b128; half-wave (32-lane) shfl reductions.
  {
    const int b5 = tid & 31;          // column group (cols b5*4 .. +4)
    const int h  = tid >> 5;
#pragma unroll
    for (int k = 0; k < 8; ++k) {
      const int row = h + k * 8;
      const f32x4 a4 = *(const f32x4*)(stage + tid * 16 + k * 4096);
      const f32x4 e4 = *(const f32x4*)(stage + 32768 + tid * 16 + k * 4096);
      const f32x4 q4 = *(const f32x4*)((const float*)(ws + QSUM_OFF) +
                                       s_lab[row] * 128 + b5 * 4);
      float a2 = a4.x*a4.x + a4.y*a4.y + a4.z*a4.z + a4.w*a4.w;
      float e2 = e4.x*e4.x + e4.y*e4.y + e4.z*e4.z + e4.w*e4.w;
      float ae = a4.x*e4.x + a4.y*e4.y + a4.z*e4.z + a4.w*e4.w;
      float pd = a4.x*q4.x + a4.y*q4.y + a4.z*q4.z + a4.w*q4.w;
#pragma unroll
      for (int m = 1; m < 32; m <<= 1) {
        a2 += __shfl_xor(a2, m);
        e2 += __shfl_xor(e2, m);
        ae += __shfl_xor(ae, m);
        pd += __shfl_xor(pd, m);
      }
      const float rna = rsqrtf(a2), rne = rsqrtf(e2);
      if (b5 == 0) {
        s_lpos[row] = ae * rna * rne * C2L;
        s_pd[row]   = pd * rna;
      }
      // pack 4 cols of this row into the MX frag image
      const float sc = rna * C2L;     // MFMA output becomes 2s/ln2
      const int st = row >> 4, tl = (b5 >> 3) * 16 + (row & 15);
      *(unsigned*)(aT + st * 2048 + tl * 32 + (b5 & 7) * 4) =
          pk8(a4.x * sc, a4.y * sc, a4.z * sc, a4.w * sc);
    }
  }
  __syncthreads();

  // ---- A fragments: 4 sets (64 rows) per wave, 32 B/lane (K=128 operand)
  i32x8 sa[4];
#pragma unroll
  for (int s = 0; s < 4; ++s)
    sa[s] = *(const i32x8*)(aT + s * 2048 + lane * 32);

  float dn[4][4] = {{0.f,0.f,0.f,0.f},{0.f,0.f,0.f,0.f},
                    {0.f,0.f,0.f,0.f},{0.f,0.f,0.f,0.f}};
  const f32x4 Z = {0.f, 0.f, 0.f, 0.f};
  const char* qp = ws + (size_t)(wave * GPW) * 2048 + (size_t)lane * 32;

  i32x8 B0, B1, B2;
#define LOADG(X, G)  { X = *(const i32x8*)(qp + (G) * 2048); }
#define COMPG(X)                                                        \
  { _Pragma("unroll")                                                   \
    for (int s = 0; s < 4; ++s) {                                       \
      f32x4 c = __builtin_amdgcn_mfma_scale_f32_16x16x128_f8f6f4(       \
          sa[s], X, Z, 0, 0, 0, USCALE, 0, USCALE);                     \
      _Pragma("unroll")                                                 \
      for (int rg = 0; rg < 4; ++rg) dn[s][rg] += fexp2(c[rg]);         \
    } }

  LOADG(B0, 0)
  LOADG(B1, 1)
  LOADG(B2, 2)
#pragma unroll 1
  for (int g = 0; g < GPW - 3; g += 3) {
    COMPG(B0) LOADG(B0, g + 3)
    COMPG(B1) LOADG(B1, g + 4)
    COMPG(B2) LOADG(B2, g + 5)
  }
  COMPG(B0)
  COMPG(B1)
  COMPG(B2)
#undef LOADG
#undef COMPG

  // reduce across the 16 q-column lanes of each row
#pragma unroll
  for (int s = 0; s < 4; ++s)
#pragma unroll
    for (int rg = 0; rg < 4; ++rg)
#pragma unroll
      for (int m = 1; m < 16; m <<= 1)
        dn[s][rg] += __shfl_xor(dn[s][rg], m);

  if (lo == 0) {
#pragma unroll
    for (int s = 0; s < 4; ++s)
#pragma unroll
      for (int rg = 0; rg < 4; ++rg)
        dnp[wave][s * 16 + hi * 4 + rg] = dn[s][rg];
  }
  __syncthreads();

  // epilogue: thread i (< 64) owns block-row i; partial -> plain store
  if (tid < 64) {
    const int i = tid;
    const float dtot = dnp[0][i] + dnp[1][i] + dnp[2][i] + dnp[3][i];
    const float lp   = exp2f(s_lpos[i]);        // exp(2*<f,ema_f>)
    const float dnf  = lp + dtot - (float)NPAD;
    float loss = -logf(lp / dnf + 1e-8f) + 150.0f * logf(dnf) - 2.0f * s_pd[i];
#pragma unroll
    for (int m = 1; m < 64; m <<= 1) loss += __shfl_xor(loss, m);
    if (tid == 0)
      ((float*)(ws + PART_OFF))[blockIdx.x] = loss;   // no atomic
  }
}

// ---- finalize: one block sums the 1024 per-block partials. (unchanged)
__global__ __launch_bounds__(1024) void finalize(
    const char* __restrict__ ws, float* __restrict__ out)
{
  __shared__ float sred[16];
  const int tid = threadIdx.x;
  float v = ((const float*)(ws + PART_OFF))[tid];
#pragma unroll
  for (int m = 1; m < 64; m <<= 1) v += __shfl_xor(v, m);
  if ((tid & 63) == 0) sred[tid >> 6] = v;
  __syncthreads();
  if (tid < 16) {
    float s = sred[tid];
#pragma unroll
    for (int m = 1; m < 16; m <<= 1) s += __shfl_xor(s, m);
    if (tid == 0) *out = s * (1.0f / (151.0f * 65536.0f));
  }
}

extern "C" void kernel_launch(void* const* d_in, const int* in_sizes, int n_in,
                              void* d_out, int out_size, void* d_ws, size_t ws_size,
                              hipStream_t stream) {
  const float* act   = (const float*)d_in[0];
  const float* ema   = (const float*)d_in[1];
  const float* plab  = (const float*)d_in[2];
  const float* queue = (const float*)d_in[3];
  float* out = (float*)d_out;

  prep_q8<<<dim3(NGRP + CLASS_NUM), dim3(256), 0, stream>>>(queue, (char*)d_ws);

  pgc_stream<<<dim3(NBLK), dim3(256), 0, stream>>>(act, ema, plab, (char*)d_ws);

  finalize<<<dim3(1), dim3(1024), 0, stream>>>((const char*)d_ws, out);
}